// Round 1
// baseline (463.067 us; speedup 1.0000x reference)
//
#include <hip/hip_runtime.h>

// ---------- types ----------
typedef __attribute__((ext_vector_type(8))) short s8b;   // 8 bf16 raw-bit fragment (4 VGPR)
typedef __attribute__((ext_vector_type(4))) float f32x4;

#define MFMA_BF16(a, b, c) __builtin_amdgcn_mfma_f32_16x16x32_bf16((a), (b), (c), 0, 0, 0)

// fp32 -> bf16 raw bits, round-to-nearest-even
__device__ __forceinline__ short f2bf(float f) {
    unsigned u = __float_as_uint(f);
    u += 0x7fffu + ((u >> 16) & 1u);
    return (short)(u >> 16);
}

// =====================================================================
// GEMM: C[M=8192][N=512] = A[M][K] * W[K][512] + bias, epilogue scale.
// OMODE 0: bf16 out row-major [8192][512]
// OMODE 1: bf16 out transposed for V: Vt[(b*512 + n)][kv]  (b=row>>10, kv=row&1023)
// OMODE 2: fp32 out row-major (final projection)
// ABF16: A is bf16 (short*) instead of fp32
// Tile 128x128, BK=32, 4 waves each owning a 64x64 sub-tile (4x4 MFMA frags).
// =====================================================================
template <int OMODE, bool ABF16>
__global__ __launch_bounds__(256) void gemm_k(const void* __restrict__ Ain,
                                              const float* __restrict__ W,
                                              const float* __restrict__ bias,
                                              void* __restrict__ Cout,
                                              int K, float scale) {
    __shared__ short As[128][40];   // +8 pad: row stride 80B -> max 2-way bank alias (free)
    __shared__ short Bs[128][40];   // stored TRANSPOSED: Bs[n][k]

    const int tid  = threadIdx.x;
    const int lane = tid & 63;
    const int wid  = tid >> 6;
    const int l15  = lane & 15, lhi = lane >> 4;
    const int wr   = wid >> 1, wc = wid & 1;
    const int bm   = blockIdx.x << 7;
    const int bn   = blockIdx.y << 7;

    const f32x4 zf = {0.f, 0.f, 0.f, 0.f};
    f32x4 acc[4][4];
#pragma unroll
    for (int i = 0; i < 4; ++i)
#pragma unroll
        for (int j = 0; j < 4; ++j) acc[i][j] = zf;

    const int arow = tid >> 1;          // 0..127
    const int ak0  = (tid & 1) << 4;    // 0 / 16
    const int bn_t = tid & 127;         // output col within tile
    const int bk0  = (tid >> 7) << 4;   // 0 / 16

    const int nkt = K >> 5;
    for (int kt = 0; kt < nkt; ++kt) {
        __syncthreads();
        // ---- stage A tile (128 x 32) ----
        if (ABF16) {
            const short* src = (const short*)Ain + (size_t)(bm + arow) * K + (kt << 5) + ak0;
            *(s8b*)&As[arow][ak0]     = *(const s8b*)(src);
            *(s8b*)&As[arow][ak0 + 8] = *(const s8b*)(src + 8);
        } else {
            const float* src = (const float*)Ain + (size_t)(bm + arow) * K + (kt << 5) + ak0;
            s8b t0, t1;
#pragma unroll
            for (int i = 0; i < 8; ++i) { t0[i] = f2bf(src[i]); t1[i] = f2bf(src[i + 8]); }
            *(s8b*)&As[arow][ak0]     = t0;
            *(s8b*)&As[arow][ak0 + 8] = t1;
        }
        // ---- stage B tile transposed: Bs[n][k] <- W[kt*32+k][bn+n] ----
        {
            s8b t0, t1;
#pragma unroll
            for (int j = 0; j < 8; ++j)
                t0[j] = f2bf(W[(size_t)((kt << 5) + bk0 + j) * 512 + bn + bn_t]);
#pragma unroll
            for (int j = 0; j < 8; ++j)
                t1[j] = f2bf(W[(size_t)((kt << 5) + bk0 + 8 + j) * 512 + bn + bn_t]);
            *(s8b*)&Bs[bn_t][bk0]     = t0;
            *(s8b*)&Bs[bn_t][bk0 + 8] = t1;
        }
        __syncthreads();
        // ---- MFMA ----
        s8b a[4], b[4];
#pragma unroll
        for (int rt = 0; rt < 4; ++rt)
            a[rt] = *(const s8b*)&As[(wr << 6) + (rt << 4) + l15][lhi << 3];
#pragma unroll
        for (int ct = 0; ct < 4; ++ct)
            b[ct] = *(const s8b*)&Bs[(wc << 6) + (ct << 4) + l15][lhi << 3];
#pragma unroll
        for (int rt = 0; rt < 4; ++rt)
#pragma unroll
            for (int ct = 0; ct < 4; ++ct)
                acc[rt][ct] = MFMA_BF16(a[rt], b[ct], acc[rt][ct]);
    }

    // ---- epilogue: D[row][col] with row=(lhi*4+r within 16-tile), col=l15 ----
#pragma unroll
    for (int rt = 0; rt < 4; ++rt)
#pragma unroll
        for (int ct = 0; ct < 4; ++ct) {
            const int col  = bn + (wc << 6) + (ct << 4) + l15;
            const float bv = bias[col];
#pragma unroll
            for (int r = 0; r < 4; ++r) {
                const int row = bm + (wr << 6) + (rt << 4) + (lhi << 2) + r;
                const float v = (acc[rt][ct][r] + bv) * scale;
                if (OMODE == 0) {
                    ((short*)Cout)[(size_t)row * 512 + col] = f2bf(v);
                } else if (OMODE == 1) {
                    const int bb = row >> 10, kv = row & 1023;
                    ((short*)Cout)[((size_t)(bb * 512 + col) << 10) + kv] = f2bf(v);
                } else {
                    ((float*)Cout)[(size_t)row * 512 + col] = v;
                }
            }
        }
}

// =====================================================================
// Attention: per wave, 32 q-rows of one (b,h). Two sweeps over 16 K-tiles
// of 64 kv each. Scores arrive already in log2 domain (Q pre-scaled by
// log2(e)/sqrt(HD)). Sweep 1: per-lane online max/sum, then 16-lane
// butterfly reduce. Sweep 2: recompute S, write normalized P (fp32) to the
// attention output, transpose P via per-wave LDS into A-frags, PV-MFMA.
// Vt layout: [(b*8+h)*64 + d][1024 kv]  -> contiguous B-operand loads.
// =====================================================================
__global__ __launch_bounds__(256) void attn_k(const short* __restrict__ Qp,
                                              const short* __restrict__ Kp,
                                              const short* __restrict__ Vt,
                                              float* __restrict__ attn,
                                              short* __restrict__ Oint) {
    __shared__ short Plds[4][32][72];  // per-wave P transpose buffer (+8 pad)

    const int tid = threadIdx.x;
    const int wid = tid >> 6, lane = tid & 63;
    const int l15 = lane & 15, lhi = lane >> 4;
    const int bid = blockIdx.x;               // 512 blocks = 8 qc * 8 h * 8 b
    const int qc = bid & 7, h = (bid >> 3) & 7, b = bid >> 6;
    const int q0 = (qc << 7) + (wid << 5);    // this wave's first q-row

    // Q fragments (A-operand): row = l15 (+rt*16), k(d) = ks*32 + lhi*8 + j
    const size_t qbase = ((size_t)(b * 1024 + q0)) * 512 + h * 64;
    s8b aq[2][2];
#pragma unroll
    for (int rt = 0; rt < 2; ++rt)
#pragma unroll
        for (int ks = 0; ks < 2; ++ks)
            aq[rt][ks] = *(const s8b*)&Qp[qbase + (size_t)((rt << 4) + l15) * 512 + (ks << 5) + (lhi << 3)];

    float m8[8], l8[8];
#pragma unroll
    for (int i = 0; i < 8; ++i) { m8[i] = -1e30f; l8[i] = 0.f; }

    const size_t kbase = ((size_t)(b * 1024)) * 512 + h * 64;

    // ---------------- sweep 1: max + sum ----------------
    for (int kt = 0; kt < 16; ++kt) {
        s8b bk[4][2];
#pragma unroll
        for (int c = 0; c < 4; ++c)
#pragma unroll
            for (int ks = 0; ks < 2; ++ks)
                bk[c][ks] = *(const s8b*)&Kp[kbase + (size_t)((kt << 6) + (c << 4) + l15) * 512 + (ks << 5) + (lhi << 3)];
        const f32x4 zf = {0.f, 0.f, 0.f, 0.f};
        f32x4 s[2][4];
#pragma unroll
        for (int rt = 0; rt < 2; ++rt)
#pragma unroll
            for (int c = 0; c < 4; ++c) {
                s[rt][c] = zf;
                s[rt][c] = MFMA_BF16(aq[rt][0], bk[c][0], s[rt][c]);
                s[rt][c] = MFMA_BF16(aq[rt][1], bk[c][1], s[rt][c]);
            }
#pragma unroll
        for (int rt = 0; rt < 2; ++rt)
#pragma unroll
            for (int r = 0; r < 4; ++r) {
                const int idx = (rt << 2) + r;
                const float v0 = s[rt][0][r], v1 = s[rt][1][r];
                const float v2 = s[rt][2][r], v3 = s[rt][3][r];
                const float vm = fmaxf(fmaxf(v0, v1), fmaxf(v2, v3));
                const float mn = fmaxf(m8[idx], vm);
                const float corr = exp2f(m8[idx] - mn);
                const float add = exp2f(v0 - mn) + exp2f(v1 - mn) + exp2f(v2 - mn) + exp2f(v3 - mn);
                l8[idx] = l8[idx] * corr + add;
                m8[idx] = mn;
            }
    }
    // butterfly across the 16 lanes (bits 0..3) that share each row
#pragma unroll
    for (int i = 0; i < 8; ++i) {
        float m = m8[i], l = l8[i];
#pragma unroll
        for (int mask = 1; mask <= 8; mask <<= 1) {
            const float mo = __shfl_xor(m, mask, 64);
            const float lo = __shfl_xor(l, mask, 64);
            const float mn = fmaxf(m, mo);
            l = l * exp2f(m - mn) + lo * exp2f(mo - mn);
            m = mn;
        }
        m8[i] = m;
        l8[i] = 1.0f / l;  // store inverse sum
    }

    // ---------------- sweep 2: P write + PV ----------------
    const f32x4 zf = {0.f, 0.f, 0.f, 0.f};
    f32x4 o[2][4];
#pragma unroll
    for (int rt = 0; rt < 2; ++rt)
#pragma unroll
        for (int cd = 0; cd < 4; ++cd) o[rt][cd] = zf;

    const size_t vbase = ((size_t)(((b << 3) + h) << 6)) << 10;          // (b*8+h)*64*1024
    const size_t abase = ((size_t)(((b << 3) + h) * 1024 + q0)) << 10;   // attention row base

    for (int kt = 0; kt < 16; ++kt) {
        // recompute S (identical to sweep 1)
        s8b bk[4][2];
#pragma unroll
        for (int c = 0; c < 4; ++c)
#pragma unroll
            for (int ks = 0; ks < 2; ++ks)
                bk[c][ks] = *(const s8b*)&Kp[kbase + (size_t)((kt << 6) + (c << 4) + l15) * 512 + (ks << 5) + (lhi << 3)];
        f32x4 s[2][4];
#pragma unroll
        for (int rt = 0; rt < 2; ++rt)
#pragma unroll
            for (int c = 0; c < 4; ++c) {
                s[rt][c] = zf;
                s[rt][c] = MFMA_BF16(aq[rt][0], bk[c][0], s[rt][c]);
                s[rt][c] = MFMA_BF16(aq[rt][1], bk[c][1], s[rt][c]);
            }
        // normalize: p = 2^(s - m) * invl
#pragma unroll
        for (int rt = 0; rt < 2; ++rt)
#pragma unroll
            for (int c = 0; c < 4; ++c)
#pragma unroll
                for (int r = 0; r < 4; ++r) {
                    const int idx = (rt << 2) + r;
                    s[rt][c][r] = exp2f(s[rt][c][r] - m8[idx]) * l8[idx];
                }
        // write attention (fp32) + stage P into per-wave LDS for transpose
#pragma unroll
        for (int rt = 0; rt < 2; ++rt)
#pragma unroll
            for (int r = 0; r < 4; ++r) {
                const int prow = (rt << 4) + (lhi << 2) + r;
                const size_t ar = abase + ((size_t)prow << 10) + (kt << 6);
#pragma unroll
                for (int c = 0; c < 4; ++c) {
                    attn[ar + (c << 4) + l15] = s[rt][c][r];
                    Plds[wid][prow][(c << 4) + l15] = f2bf(s[rt][c][r]);
                }
            }
        // P as A-operand (same-wave LDS dependency; compiler inserts lgkmcnt)
        s8b pa[2][2], bv[4][2];
#pragma unroll
        for (int rt = 0; rt < 2; ++rt)
#pragma unroll
            for (int ks = 0; ks < 2; ++ks)
                pa[rt][ks] = *(const s8b*)&Plds[wid][(rt << 4) + l15][(ks << 5) + (lhi << 3)];
        // V as B-operand from transposed Vt: contiguous 16B loads
#pragma unroll
        for (int cd = 0; cd < 4; ++cd)
#pragma unroll
            for (int ks = 0; ks < 2; ++ks)
                bv[cd][ks] = *(const s8b*)&Vt[vbase + (size_t)((cd << 4) + l15) * 1024 + (kt << 6) + (ks << 5) + (lhi << 3)];
#pragma unroll
        for (int rt = 0; rt < 2; ++rt)
#pragma unroll
            for (int cd = 0; cd < 4; ++cd) {
                o[rt][cd] = MFMA_BF16(pa[rt][0], bv[cd][0], o[rt][cd]);
                o[rt][cd] = MFMA_BF16(pa[rt][1], bv[cd][1], o[rt][cd]);
            }
    }

    // write O intermediate (bf16, [8192][512] with col = h*64+d)
#pragma unroll
    for (int rt = 0; rt < 2; ++rt)
#pragma unroll
        for (int cd = 0; cd < 4; ++cd)
#pragma unroll
            for (int r = 0; r < 4; ++r) {
                const size_t orow =
                    ((size_t)(b * 1024 + q0 + (rt << 4) + (lhi << 2) + r)) * 512 + h * 64 + (cd << 4) + l15;
                Oint[orow] = f2bf(o[rt][cd][r]);
            }
}

// =====================================================================
extern "C" void kernel_launch(void* const* d_in, const int* in_sizes, int n_in,
                              void* d_out, int out_size, void* d_ws, size_t ws_size,
                              hipStream_t stream) {
    (void)in_sizes; (void)n_in; (void)out_size; (void)ws_size;

    const float* query = (const float*)d_in[0];
    const float* key   = (const float*)d_in[1];
    const float* value = (const float*)d_in[2];
    const float* Wq = (const float*)d_in[3];
    const float* bq = (const float*)d_in[4];
    const float* Wk = (const float*)d_in[5];
    const float* bk = (const float*)d_in[6];
    const float* Wv = (const float*)d_in[7];
    const float* bv = (const float*)d_in[8];
    const float* Wo = (const float*)d_in[9];
    const float* bo = (const float*)d_in[10];

    float* out  = (float*)d_out;
    float* attn = out + (size_t)8 * 1024 * 512;   // output 1 starts after output 0

    char* ws    = (char*)d_ws;
    short* Qp   = (short*)(ws);                   //  8 MiB: [8192][512] bf16, pre-scaled by log2e/8
    short* Kp   = (short*)(ws + (8u << 20));      //  8 MiB: [8192][512] bf16
    short* Vt   = (short*)(ws + (16u << 20));     //  8 MiB: [(b*8+h)*64 + d][1024] bf16
    short* Oint = (short*)(ws + (24u << 20));     //  8 MiB: [8192][512] bf16

    const dim3 blk(256);
    const dim3 gg(64, 4);
    const float qscale = 0.18033688011112042f;    // log2(e) / sqrt(HD=64)

    gemm_k<0, false><<<gg, blk, 0, stream>>>(query, Wq, bq, Qp, 512, qscale);
    gemm_k<0, false><<<gg, blk, 0, stream>>>(key,   Wk, bk, Kp, 256, 1.0f);
    gemm_k<1, false><<<gg, blk, 0, stream>>>(value, Wv, bv, Vt, 256, 1.0f);
    attn_k<<<dim3(512), blk, 0, stream>>>(Qp, Kp, Vt, attn, Oint);
    gemm_k<2, true><<<gg, blk, 0, stream>>>(Oint, Wo, bo, out, 512, 1.0f);
}